// Round 17
// baseline (55.596 us; speedup 1.0000x reference)
//
#include <hip/hip_runtime.h>
#include <math.h>

// ws layout (float offsets) — every slot written fresh each call, no atomics
#define WS_FOCALP 0        // 2048 focal block partials
#define WS_CONSP  2048     // 6*2048 consensus partials, [k][b]
#define WS_AREAP  14336    // 512 (img*16+part)
#define WS_EXP_   14848    // 512
#define WS_EYP_   15360    // 512
#define WS_POS    15872    // 1024
#define WS_PART   16896    // 1024*64 float2 (m,s) -> 131072 floats (ends 147968)
// bf16 planes (byte offsets into ws), FRAGMENT-TILED:
//   plane = [rg(64)][kb(16)] tiles; tile = 1KB; byte l*16 of tile = fragment
//   of lane l: row rg*16+(l&15), k = kb*32+(l>>4)*8 .. +7.
#define WS_HI_B   1048576
#define WS_LO_B   2621440

typedef __attribute__((ext_vector_type(8))) short bf16x8;
typedef __attribute__((ext_vector_type(4))) float f32x4;

#define MFMA16(a, b, c) __builtin_amdgcn_mfma_f32_16x16x32_bf16((a), (b), (c), 0, 0, 0)

__device__ inline float wave_reduce(float v) {
#pragma unroll
  for (int m = 32; m >= 1; m >>= 1) v += __shfl_xor(v, m);
  return v;
}

__device__ inline void lse_merge(float& m, float& s, float m2, float s2) {
  float nm = fmaxf(m, m2);
  s = s * __expf(m - nm) + s2 * __expf(m2 - nm);
  m = nm;
}

__device__ inline unsigned short bf16_rne(float x) {
  union { float f; unsigned u; } v; v.f = x;
  unsigned r = v.u + 0x7FFF + ((v.u >> 16) & 1);
  return (unsigned short)(r >> 16);
}
__device__ inline float bf16_f(unsigned short h) {
  union { unsigned u; float f; } v; v.u = ((unsigned)h) << 16; return v.f;
}

__device__ inline float focal_px(float v0, float v1, float v2, float v3,
                                 float v4, float v5, float v6, float v7, int tt) {
  float mx = fmaxf(fmaxf(fmaxf(v0, v1), fmaxf(v2, v3)),
                   fmaxf(fmaxf(v4, v5), fmaxf(v6, v7)));
  float se = __expf(v0 - mx) + __expf(v1 - mx) + __expf(v2 - mx) + __expf(v3 - mx) +
             __expf(v4 - mx) + __expf(v5 - mx) + __expf(v6 - mx) + __expf(v7 - mx);
  float xt = v0;
  xt = (tt == 1) ? v1 : xt;
  xt = (tt == 2) ? v2 : xt;
  xt = (tt == 3) ? v3 : xt;
  xt = (tt == 4) ? v4 : xt;
  xt = (tt == 5) ? v5 : xt;
  xt = (tt == 6) ? v6 : xt;
  xt = (tt == 7) ? v7 : xt;
  float lp = (xt - mx) - __logf(se);
  float p = __expf(lp);
  float om = 1.0f - p;
  return 0.25f * om * om * (-lp);
}

// ---------- mega: streaming + prep ----------
// blocks [0,2048): focal | [2048,2560): circularity | [2560,4608): consensus
// [4608,4864): prep — feature norms + normalized bf16 hi/lo, FRAGMENT-TILED
__global__ __launch_bounds__(256) void mega_kernel(
    const float* __restrict__ logits, const int* __restrict__ target,
    const float* __restrict__ feat, const float* __restrict__ masks,
    const float* __restrict__ preds, float* __restrict__ ws) {
  __shared__ float red[32];
  const int bid = blockIdx.x;
  const int tid = threadIdx.x;
  const int lane = tid & 63;
  const int wid = tid >> 6;

  if (bid < 2048) {
    // ---------------- focal ----------------
    int t = bid * 256 + tid;
    int p4 = t * 4;
    int b = p4 >> 16;
    int hw = p4 & 65535;
    const float* lb = logits + (b << 19) + hw;
    float4 x0 = *(const float4*)(lb + (0 << 16));
    float4 x1 = *(const float4*)(lb + (1 << 16));
    float4 x2 = *(const float4*)(lb + (2 << 16));
    float4 x3 = *(const float4*)(lb + (3 << 16));
    float4 x4 = *(const float4*)(lb + (4 << 16));
    float4 x5 = *(const float4*)(lb + (5 << 16));
    float4 x6 = *(const float4*)(lb + (6 << 16));
    float4 x7 = *(const float4*)(lb + (7 << 16));
    int4 tg = *(const int4*)(target + p4);
    float acc = 0.0f;
    acc += focal_px(x0.x, x1.x, x2.x, x3.x, x4.x, x5.x, x6.x, x7.x, tg.x);
    acc += focal_px(x0.y, x1.y, x2.y, x3.y, x4.y, x5.y, x6.y, x7.y, tg.y);
    acc += focal_px(x0.z, x1.z, x2.z, x3.z, x4.z, x5.z, x6.z, x7.z, tg.z);
    acc += focal_px(x0.w, x1.w, x2.w, x3.w, x4.w, x5.w, x6.w, x7.w, tg.w);
    float v = wave_reduce(acc);
    if (lane == 0) red[wid] = v;
    __syncthreads();
    if (tid == 0) ws[WS_FOCALP + bid] = red[0] + red[1] + red[2] + red[3];

  } else if (bid < 2560) {
    // ---------------- circularity ----------------
    int bi = bid - 2048;
    int img = bi >> 4;
    int part = bi & 15;
    const float* mS = masks + img * 3 * 65536;
    const float4* m4 = (const float4*)mS;
    float a = 0.0f, ex = 0.0f, ey = 0.0f;
#pragma unroll
    for (int i = 0; i < 4; i++) {
      int v = tid + 256 * i;
      int rl = v >> 6;
      int c4 = v & 63;
      int row = part * 16 + rl;
      float4 val = m4[row * 64 + c4];
      a += val.x + val.y + val.z + val.w;
      ey += fabsf(val.y - val.x) + fabsf(val.z - val.y) + fabsf(val.w - val.z);
      if (c4 > 0) ey += fabsf(val.x - mS[row * 256 + c4 * 4 - 1]);
      if (row > 0) {
        float4 u = m4[(row - 1) * 64 + c4];
        ex += fabsf(val.x - u.x) + fabsf(val.y - u.y) +
              fabsf(val.z - u.z) + fabsf(val.w - u.w);
      }
    }
    float ra = wave_reduce(a);
    float rx = wave_reduce(ex);
    float ry = wave_reduce(ey);
    if (lane == 0) {
      red[wid + 0] = ra; red[wid + 4] = rx; red[wid + 8] = ry;
    }
    __syncthreads();
    if (tid == 0) {
      ws[WS_AREAP + bi] = red[0] + red[1] + red[2] + red[3];
      ws[WS_EXP_ + bi] = red[4] + red[5] + red[6] + red[7];
      ws[WS_EYP_ + bi] = red[8] + red[9] + red[10] + red[11];
    }

  } else if (bid < 4608) {
    // ---------------- consensus ----------------
    int b = bid - 2560;
    int t = b * 256 + tid;
    const float4* q = (const float4*)preds;
    float4 a0 = q[t];
    float4 a1 = q[t + 524288];
    float4 a2 = q[t + 1048576];
    float s0 = a0.x + a0.y + a0.z + a0.w;
    float s1 = a1.x + a1.y + a1.z + a1.w;
    float s2 = a2.x + a2.y + a2.z + a2.w;
    float p01 = a0.x * a1.x + a0.y * a1.y + a0.z * a1.z + a0.w * a1.w;
    float p02 = a0.x * a2.x + a0.y * a2.y + a0.z * a2.z + a0.w * a2.w;
    float p12 = a1.x * a2.x + a1.y * a2.y + a1.z * a2.z + a1.w * a2.w;
    float r0 = wave_reduce(s0);
    float r1 = wave_reduce(s1);
    float r2 = wave_reduce(s2);
    float r3 = wave_reduce(p01);
    float r4 = wave_reduce(p02);
    float r5 = wave_reduce(p12);
    if (lane == 0) {
      red[wid + 0] = r0; red[wid + 4] = r1; red[wid + 8] = r2;
      red[wid + 12] = r3; red[wid + 16] = r4; red[wid + 20] = r5;
    }
    __syncthreads();
    if (tid == 0) {
#pragma unroll
      for (int k = 0; k < 6; k++)
        ws[WS_CONSP + k * 2048 + b] =
            red[k * 4] + red[k * 4 + 1] + red[k * 4 + 2] + red[k * 4 + 3];
    }

  } else {
    // ------- prep: norms + bf16 hi/lo split, FRAGMENT-TILED -------
    int row = (bid - 4608) * 4 + wid;  // 0..1023
    const float4* f4 = (const float4*)feat;
    float4 u = f4[row * 128 + lane];       // k = 4*lane .. +3
    float4 w = f4[row * 128 + 64 + lane];  // k = 256+4*lane .. +3
    float s = u.x * u.x + u.y * u.y + u.z * u.z + u.w * u.w +
              w.x * w.x + w.y * w.y + w.z * w.z + w.w * w.w;
    s = wave_reduce(s);
    // scale = (1/|f|) * sqrt(1/0.07) so that g.g^T == sim/T directly
    float scale = 3.7796447300922719f / sqrtf(s);
    float g[8] = {u.x * scale, u.y * scale, u.z * scale, u.w * scale,
                  w.x * scale, w.y * scale, w.z * scale, w.w * scale};
    unsigned short h[8];
    unsigned short l[8];
#pragma unroll
    for (int i = 0; i < 8; i++) {
      h[i] = bf16_rne(g[i]);
      l[i] = bf16_rne(g[i] - bf16_f(h[i]));
    }
    // tiled addr: elem (row,k) -> tile(row>>4, k>>5)*1KB
    //   + slot(((k>>3)&3)*16 + (row&15))*16 + (k&7)*2
    const int rg = row >> 4, r15 = row & 15;
    int k0 = lane * 4;
    int k1 = 256 + lane * 4;
    int off0 = (rg * 16 + (k0 >> 5)) * 1024 + (((k0 >> 3) & 3) * 16 + r15) * 16 + (k0 & 7) * 2;
    int off1 = (rg * 16 + (k1 >> 5)) * 1024 + (((k1 >> 3) & 3) * 16 + r15) * 16 + (k1 & 7) * 2;
    char* hb = (char*)ws + WS_HI_B;
    char* lb = (char*)ws + WS_LO_B;
    *(ushort4*)(hb + off0) = make_ushort4(h[0], h[1], h[2], h[3]);
    *(ushort4*)(hb + off1) = make_ushort4(h[4], h[5], h[6], h[7]);
    *(ushort4*)(lb + off0) = make_ushort4(l[0], l[1], l[2], l[3]);
    *(ushort4*)(lb + off1) = make_ushort4(l[4], l[5], l[6], l[7]);
  }
}

// ---------- sim: SYMMETRIC upper-triangle, 32x32 tiles, K split 4-ways ----
// C = G.G^T is symmetric: compute rt<=ct only (528 blocks), emit each tile's
// LSE partials twice (row-wise + transposed col-wise). Halves loads & MFMAs:
// 67.6 MB issued vs 196 MB. 4 waves/block each do 4 k-steps (8 coalesced
// 1KB loads + 12 MFMAs per step); partial accs summed via padded LDS; each
// wave epilogues one 16x16 sub-tile. WS_PART granularity: 64 groups of 16.
__global__ __launch_bounds__(256) void sim_kernel(float* __restrict__ ws) {
  __shared__ float accs[4][64][17];  // [kwave][lane][2x2 f32x4], stride 17
  const int tid = threadIdx.x;
  const int lane = tid & 63;
  const int wid = tid >> 6;  // k-quarter
  // decode upper-triangle block index -> (rt, ct), rt<=ct over 32 groups
  int b = blockIdx.x, rt = 0;
  while (b >= 32 - rt) { b -= 32 - rt; rt++; }
  const int ct = rt + b;
  const int l15 = lane & 15;
  const int hi8 = lane >> 4;
  const char* HI = (const char*)ws + WS_HI_B;
  const char* LO = (const char*)ws + WS_LO_B;
  const int kb0 = wid * 4;  // this wave's k-step base
  const int lb16 = lane * 16;
  const char* pAh0 = HI + ((2 * rt + 0) * 16 + kb0) * 1024 + lb16;
  const char* pAh1 = HI + ((2 * rt + 1) * 16 + kb0) * 1024 + lb16;
  const char* pAl0 = LO + ((2 * rt + 0) * 16 + kb0) * 1024 + lb16;
  const char* pAl1 = LO + ((2 * rt + 1) * 16 + kb0) * 1024 + lb16;
  const char* pBh0 = HI + ((2 * ct + 0) * 16 + kb0) * 1024 + lb16;
  const char* pBh1 = HI + ((2 * ct + 1) * 16 + kb0) * 1024 + lb16;
  const char* pBl0 = LO + ((2 * ct + 0) * 16 + kb0) * 1024 + lb16;
  const char* pBl1 = LO + ((2 * ct + 1) * 16 + kb0) * 1024 + lb16;

  f32x4 acc[2][2];
#pragma unroll
  for (int r = 0; r < 2; r++)
#pragma unroll
    for (int c = 0; c < 2; c++) acc[r][c] = (f32x4){0.f, 0.f, 0.f, 0.f};

#pragma unroll
  for (int k4 = 0; k4 < 4; k4++) {
    const int o = k4 * 1024;
    bf16x8 ah0 = *(const bf16x8*)(pAh0 + o);
    bf16x8 ah1 = *(const bf16x8*)(pAh1 + o);
    bf16x8 al0 = *(const bf16x8*)(pAl0 + o);
    bf16x8 al1 = *(const bf16x8*)(pAl1 + o);
    bf16x8 bh0 = *(const bf16x8*)(pBh0 + o);
    bf16x8 bh1 = *(const bf16x8*)(pBh1 + o);
    bf16x8 bl0 = *(const bf16x8*)(pBl0 + o);
    bf16x8 bl1 = *(const bf16x8*)(pBl1 + o);
    acc[0][0] = MFMA16(ah0, bh0, acc[0][0]);
    acc[0][0] = MFMA16(ah0, bl0, acc[0][0]);
    acc[0][0] = MFMA16(al0, bh0, acc[0][0]);
    acc[0][1] = MFMA16(ah0, bh1, acc[0][1]);
    acc[0][1] = MFMA16(ah0, bl1, acc[0][1]);
    acc[0][1] = MFMA16(al0, bh1, acc[0][1]);
    acc[1][0] = MFMA16(ah1, bh0, acc[1][0]);
    acc[1][0] = MFMA16(ah1, bl0, acc[1][0]);
    acc[1][0] = MFMA16(al1, bh0, acc[1][0]);
    acc[1][1] = MFMA16(ah1, bh1, acc[1][1]);
    acc[1][1] = MFMA16(ah1, bl1, acc[1][1]);
    acc[1][1] = MFMA16(al1, bh1, acc[1][1]);
  }

  // stash K-partials, then each wave epilogues tile (er,ec)
#pragma unroll
  for (int r = 0; r < 2; r++)
#pragma unroll
    for (int c = 0; c < 2; c++)
#pragma unroll
      for (int q = 0; q < 4; q++)
        accs[wid][lane][(r * 2 + c) * 4 + q] = acc[r][c][q];
  __syncthreads();

  const int er = wid >> 1, ec = wid & 1;
  float av[4];
#pragma unroll
  for (int q = 0; q < 4; q++) {
    int idx = (er * 2 + ec) * 4 + q;
    av[q] = accs[0][lane][idx] + accs[1][lane][idx] +
            accs[2][lane][idx] + accs[3][lane][idx];
  }

  float2* part = (float2*)(ws + WS_PART);
  const int col0 = 32 * ct + ec * 16 + l15;
  const bool isdiag = (rt == ct);

  // ---- row partials (+ pos, + diag mask) ----
#pragma unroll
  for (int q = 0; q < 4; q++) {
    int row = 32 * rt + er * 16 + hi8 * 4 + q;
    float x = av[q];
    int pc = (row + 512) & 1023;
    if (col0 == pc) {  // symmetric: pos[row] = pos[col] = sim[row][col]
      ws[WS_POS + row] = x;
      ws[WS_POS + col0] = x;
    }
    float xm = (isdiag && col0 == row) ? -1e30f : x;
    float m = xm, s = 1.0f;
#pragma unroll
    for (int d = 1; d < 16; d <<= 1)
      lse_merge(m, s, __shfl_xor(m, d), __shfl_xor(s, d));
    if (l15 == 0) part[row * 64 + ct * 2 + ec] = make_float2(m, s);
  }

  // ---- col partials (transposed coverage; off-diag only) ----
  if (!isdiag) {
    float m = av[0], s = 1.0f;
    lse_merge(m, s, av[1], 1.0f);
    lse_merge(m, s, av[2], 1.0f);
    lse_merge(m, s, av[3], 1.0f);
    lse_merge(m, s, __shfl_xor(m, 16), __shfl_xor(s, 16));
    lse_merge(m, s, __shfl_xor(m, 32), __shfl_xor(s, 32));
    if (hi8 == 0) part[col0 * 64 + rt * 2 + er] = make_float2(m, s);
  }
}

__global__ __launch_bounds__(1024) void final_kernel(float* __restrict__ ws,
                                                     float* __restrict__ out) {
  __shared__ float red[16][8];
  __shared__ float li_s[32];
  int r = threadIdx.x;  // 0..1023
  int lane = r & 63, wid = r >> 6;

  float v[8];
  // ---- contrastive LSE merge over 64 col-groups ----
  const float2* part = (const float2*)(ws + WS_PART);
  float M = -1e30f, S = 0.0f;
#pragma unroll
  for (int ctl = 0; ctl < 64; ctl++) {
    float2 p = part[r * 64 + ctl];
    float nm = fmaxf(M, p.x);
    S = S * __expf(M - nm) + p.y * __expf(p.x - nm);
    M = nm;
  }
  v[0] = (M + __logf(S)) - ws[WS_POS + r];
  // ---- focal partials ----
  v[1] = ws[WS_FOCALP + r] + ws[WS_FOCALP + r + 1024];
  // ---- consensus partials ----
#pragma unroll
  for (int k = 0; k < 6; k++) {
    const float* p = ws + WS_CONSP + k * 2048;
    v[2 + k] = p[r] + p[r + 1024];
  }
#pragma unroll
  for (int k = 0; k < 8; k++) {
    v[k] = wave_reduce(v[k]);
    if (lane == 0) red[wid][k] = v[k];
  }

  // ---- circularity: 32 imgs x 16 parts ----
  if (r < 512) {
    float a = ws[WS_AREAP + r];
    float ex = ws[WS_EXP_ + r];
    float ey = ws[WS_EYP_ + r];
#pragma unroll
    for (int d = 1; d < 16; d <<= 1) {
      a += __shfl_xor(a, d);
      ex += __shfl_xor(ex, d);
      ey += __shfl_xor(ey, d);
    }
    if ((r & 15) == 0) {
      float per = ex + ey;
      float dd = fmaxf(per, 1e-12f);
      float c = 12.566370614359172f * a / (dd * dd);
      li_s[r >> 4] = (a > 0.0f && per > 0.0f) ? (c - 1.0f) * (c - 1.0f) : 0.0f;
    }
  }
  __syncthreads();

  if (r == 0) {
    float tot[8];
#pragma unroll
    for (int k = 0; k < 8; k++) {
      float t = 0.0f;
#pragma unroll
      for (int i = 0; i < 16; i++) t += red[i][k];
      tot[k] = t;
    }
    float circ = 0.0f;
#pragma unroll
    for (int i = 0; i < 32; i++) circ += li_s[i];
    circ = 0.1f * circ / 32.0f;

    float contr = tot[0] / 1024.0f;
    float focal = tot[1] / 2097152.0f;

    float S0 = tot[2], S1 = tot[3], S2 = tot[4];
    float P01 = tot[5], P02 = tot[6], P12 = tot[7];
    float co = 0.0f;
    co += fmaxf(0.6f - P01 / (S0 + S1 - P01 + 1e-6f), 0.0f);
    co += fmaxf(0.6f - P02 / (S0 + S2 - P02 + 1e-6f), 0.0f);
    co += fmaxf(0.6f - P12 / (S1 + S2 - P12 + 1e-6f), 0.0f);
    co *= (1.0f / 3.0f);

    out[0] = focal + 0.5f * contr + circ + 0.3f * co;
  }
}

extern "C" void kernel_launch(void* const* d_in, const int* in_sizes, int n_in,
                              void* d_out, int out_size, void* d_ws, size_t ws_size,
                              hipStream_t stream) {
  const float* logits = (const float*)d_in[0];
  const int* target = (const int*)d_in[1];
  const float* feat = (const float*)d_in[2];
  const float* masks = (const float*)d_in[3];
  const float* preds = (const float*)d_in[4];
  float* ws = (float*)d_ws;
  float* out = (float*)d_out;

  mega_kernel<<<4864, 256, 0, stream>>>(logits, target, feat, masks, preds, ws);
  sim_kernel<<<528, 256, 0, stream>>>(ws);
  final_kernel<<<1, 1024, 0, stream>>>(ws, out);
}